// Round 11
// baseline (417.603 us; speedup 1.0000x reference)
//
#include <hip/hip_runtime.h>
#include <hip/hip_bf16.h>
#include <hip/hip_fp16.h>
#include <math.h>

// Problem constants (match reference)
#define NN 100000
#define EE 1600000
#define HH 128
#define GG 2000
#define SS 200
#define CC 10
#define NPG 50   // nodes per graph
#define PGS 10   // graphs per set
#define NCLS 128           // dst classes (one persistent block per class in count/fill)
#define CLSW 782           // ceil(NN/NCLS); 128*782 = 100096 >= NN
#define EPB 4096           // edges per histogram/scatter block
#define NBLKH 391          // ceil(EE/EPB)
#define SCAN_N (NCLS * NBLKH)   // 50048

typedef _Float16 f16x8 __attribute__((ext_vector_type(8)));
typedef float    f32x4 __attribute__((ext_vector_type(4)));

// ---------------- CSR build (deterministic binned, class-owned fill) ----------------

// Step 1: per-block per-class histogram (LDS only)
__global__ __launch_bounds__(256) void histo_kernel(const int* __restrict__ ei_dst,
                                                    int* __restrict__ blkcnt) {
    __shared__ int h[4][NCLS];
    for (int i = threadIdx.x; i < 4 * NCLS; i += 256) ((int*)h)[i] = 0;
    __syncthreads();
    int w = threadIdx.x >> 6;
    int base = blockIdx.x * EPB;
#pragma unroll
    for (int i = 0; i < 16; ++i) {
        int idx = base + i * 256 + threadIdx.x;
        if (idx < EE) {
            int d = __builtin_nontemporal_load(ei_dst + idx);
            atomicAdd(&h[w][(unsigned)d / CLSW], 1);
        }
    }
    __syncthreads();
    for (int c = threadIdx.x; c < NCLS; c += 256)
        blkcnt[c * NBLKH + blockIdx.x] = h[0][c] + h[1][c] + h[2][c] + h[3][c];
}

// generic 3-phase scan: out[i+1] = inclusive_scan(v)[i], out[0] = 0  (=> out = exclusive scan)
__global__ void scan_chunk_kernel(const int* __restrict__ v, int* __restrict__ outp,
                                  int* __restrict__ bsum, int n) {
    __shared__ int s[256];
    int tid = threadIdx.x;
    int i = blockIdx.x * 256 + tid;
    int x = (i < n) ? v[i] : 0;
    s[tid] = x;
    __syncthreads();
    for (int off = 1; off < 256; off <<= 1) {
        int y = (tid >= off) ? s[tid - off] : 0;
        __syncthreads();
        s[tid] += y;
        __syncthreads();
    }
    if (i < n) outp[i + 1] = s[tid];
    if (tid == 255) bsum[blockIdx.x] = s[255];
}

__global__ void scan_bsums_kernel(int* bsum, int nb) {
    __shared__ int s[512];
    int tid = threadIdx.x;
    int x = (tid < nb) ? bsum[tid] : 0;
    s[tid] = x;
    __syncthreads();
    for (int off = 1; off < 512; off <<= 1) {
        int y = (tid >= off) ? s[tid - off] : 0;
        __syncthreads();
        s[tid] += y;
        __syncthreads();
    }
    if (tid < nb) bsum[tid] = s[tid];
}

__global__ void scan_finish_kernel(int* __restrict__ outp, const int* __restrict__ bsum, int n) {
    int i = blockIdx.x * 256 + threadIdx.x;
    if (i < n) {
        if (blockIdx.x > 0) outp[i + 1] += bsum[blockIdx.x - 1];
    }
    if (i == 0) outp[0] = 0;
}

// Step 3: scatter edges into packed class buckets (LDS cursors only)
__global__ __launch_bounds__(256) void scatter_bin_kernel(const int* __restrict__ ei,
                                                          const int* __restrict__ blkoff,
                                                          long long* __restrict__ ebin) {
    __shared__ int cur[NCLS];
    for (int c = threadIdx.x; c < NCLS; c += 256) cur[c] = blkoff[c * NBLKH + blockIdx.x];
    __syncthreads();
    int base = blockIdx.x * EPB;
#pragma unroll
    for (int i = 0; i < 16; ++i) {
        int idx = base + i * 256 + threadIdx.x;
        if (idx < EE) {
            int s = __builtin_nontemporal_load(ei + idx);
            int d = __builtin_nontemporal_load(ei + EE + idx);
            int c = (unsigned)d / CLSW;
            int pos = atomicAdd(&cur[c], 1);
            ebin[pos] = ((long long)d << 32) | (unsigned)s;
        }
    }
}

// Step 4: one block per class: LDS degree count -> row_ptr (class-local prefix scan) + dinv.
// Replaces the global 3-kernel scan over NN.
__global__ __launch_bounds__(256) void count_dinv_kernel(const long long* __restrict__ ebin,
                                                         const int* __restrict__ blkoff,
                                                         int* __restrict__ row_ptr,
                                                         float* __restrict__ dinv) {
    __shared__ int cnt[CLSW];
    __shared__ int part[256];
    int c = blockIdx.x;
    for (int i = threadIdx.x; i < CLSW; i += 256) cnt[i] = 0;
    __syncthreads();
    int beg = blkoff[c * NBLKH];
    int end = blkoff[(c + 1) * NBLKH];   // blkoff[SCAN_N] == EE
    int n0 = c * CLSW;
    for (int k = beg + threadIdx.x; k < end; k += 256) {
        long long e = __builtin_nontemporal_load(ebin + k);
        atomicAdd(&cnt[(int)(e >> 32) - n0], 1);
    }
    __syncthreads();
    int nn = min(n0 + CLSW, NN) - n0;
    int t = threadIdx.x;
    // per-thread serial prefix over 4 slots, then block scan of partials
    int base = t * 4;
    int lpre[4];
    int lsum = 0;
#pragma unroll
    for (int i = 0; i < 4; ++i) {
        int idx = base + i;
        int v = (idx < nn) ? cnt[idx] : 0;
        lpre[i] = lsum;
        lsum += v;
    }
    part[t] = lsum;
    __syncthreads();
    for (int off = 1; off < 256; off <<= 1) {
        int y = (t >= off) ? part[t - off] : 0;
        __syncthreads();
        part[t] += y;
        __syncthreads();
    }
    int add = beg + ((t > 0) ? part[t - 1] : 0);
#pragma unroll
    for (int i = 0; i < 4; ++i) {
        int idx = base + i;
        if (idx < nn) {
            row_ptr[n0 + idx] = add + lpre[i];
            dinv[n0 + idx] = 1.0f / sqrtf((float)(cnt[idx] + 1));  // +1 self loop
        }
    }
    if (t == 0) row_ptr[n0 + nn] = end;   // class boundary (c==last writes row_ptr[NN]=EE)
}

// Step 5: one block per class: LDS cursors from row_ptr, fill col (class-owned col range).
__global__ __launch_bounds__(256) void fill_class_kernel(const long long* __restrict__ ebin,
                                                         const int* __restrict__ blkoff,
                                                         const int* __restrict__ row_ptr,
                                                         int* __restrict__ col) {
    __shared__ int cur[CLSW];
    int c = blockIdx.x;
    int n0 = c * CLSW;
    int nn = min(n0 + CLSW, NN) - n0;
    for (int i = threadIdx.x; i < nn; i += 256) cur[i] = row_ptr[n0 + i];
    __syncthreads();
    int beg = blkoff[c * NBLKH];
    int end = blkoff[(c + 1) * NBLKH];
    for (int k = beg + threadIdx.x; k < end; k += 256) {
        long long e = __builtin_nontemporal_load(ebin + k);
        int s = (int)(e & 0xffffffffll);
        int d = (int)(e >> 32);
        int o = atomicAdd(&cur[d - n0], 1);
        col[o] = s;
    }
}

// ---------------- MFMA GEMM: Y[n][128](fp16, x dinv[row]) = X[n][128] @ W[128][128] ----------

#define WTP 136

template <bool IN32>
__global__ __launch_bounds__(256) void gemm_mfma_kernel(const void* __restrict__ Xv,
                                                        const float* __restrict__ W,
                                                        const float* __restrict__ dinv,
                                                        _Float16* __restrict__ Y, int nrows) {
    __shared__ _Float16 Wt[128][WTP];   // 34.8 KB
    __shared__ _Float16 Ob[128][WTP];   // 34.8 KB
    int tid = threadIdx.x;
    int row0 = blockIdx.x * 128;

    // stage W transposed as fp16
    const float4* W4 = (const float4*)W;
#pragma unroll
    for (int it = 0; it < 16; ++it) {
        int f = it * 256 + tid;      // float4 id in [0,4096)
        int k = f >> 5;              // W row
        int c = (f & 31) << 2;       // W col (x4)
        float4 v = W4[f];
        Wt[c + 0][k] = (_Float16)v.x;
        Wt[c + 1][k] = (_Float16)v.y;
        Wt[c + 2][k] = (_Float16)v.z;
        Wt[c + 3][k] = (_Float16)v.w;
    }
    __syncthreads();

    int wave = tid >> 6;
    int l = tid & 63;
    int arow = l & 15;
    int kg = l >> 4;                 // k-group 0..3
    int baseRow = row0 + wave * 32;

    // A fragments: lane holds X[row][ks*32 + kg*8 .. +8]
    f16x8 afrag[2][4];
#pragma unroll
    for (int rt = 0; rt < 2; ++rt) {
        int r = baseRow + rt * 16 + arow;
        r = min(r, nrows - 1);
        if (IN32) {
            const float* xr = ((const float*)Xv) + (size_t)r * 128;
#pragma unroll
            for (int ks = 0; ks < 4; ++ks) {
                int k0 = ks * 32 + kg * 8;
                float4 a = ((const float4*)xr)[k0 >> 2];
                float4 b = ((const float4*)xr)[(k0 >> 2) + 1];
                f16x8 v;
                v[0] = (_Float16)a.x; v[1] = (_Float16)a.y;
                v[2] = (_Float16)a.z; v[3] = (_Float16)a.w;
                v[4] = (_Float16)b.x; v[5] = (_Float16)b.y;
                v[6] = (_Float16)b.z; v[7] = (_Float16)b.w;
                afrag[rt][ks] = v;
            }
        } else {
            const f16x8* xr = (const f16x8*)(((const _Float16*)Xv) + (size_t)r * 128);
#pragma unroll
            for (int ks = 0; ks < 4; ++ks) afrag[rt][ks] = xr[ks * 4 + kg];
        }
    }

    f32x4 acc[2][8];
#pragma unroll
    for (int rt = 0; rt < 2; ++rt)
#pragma unroll
        for (int ct = 0; ct < 8; ++ct) acc[rt][ct] = (f32x4){0.f, 0.f, 0.f, 0.f};

#pragma unroll
    for (int ct = 0; ct < 8; ++ct) {
#pragma unroll
        for (int ks = 0; ks < 4; ++ks) {
            f16x8 b = *(const f16x8*)&Wt[ct * 16 + arow][ks * 32 + kg * 8];
            acc[0][ct] = __builtin_amdgcn_mfma_f32_16x16x32_f16(afrag[0][ks], b, acc[0][ct], 0, 0, 0);
            acc[1][ct] = __builtin_amdgcn_mfma_f32_16x16x32_f16(afrag[1][ks], b, acc[1][ct], 0, 0, 0);
        }
    }

    // dinv for the 8 rows this lane owns (D: row = rt*16 + 4*kg + j, col = arow)
    float dv[2][4];
#pragma unroll
    for (int rt = 0; rt < 2; ++rt)
#pragma unroll
        for (int j = 0; j < 4; ++j) {
            int r = baseRow + rt * 16 + 4 * kg + j;
            dv[rt][j] = dinv[min(r, nrows - 1)];
        }

    // stage to LDS (own wave's 32 rows only — no block sync needed)
#pragma unroll
    for (int rt = 0; rt < 2; ++rt)
#pragma unroll
        for (int ct = 0; ct < 8; ++ct)
#pragma unroll
            for (int j = 0; j < 4; ++j)
                Ob[wave * 32 + rt * 16 + 4 * kg + j][ct * 16 + arow] =
                    (_Float16)(acc[rt][ct][j] * dv[rt][j]);

    // coalesced write-back: 8 x 16B per lane
#pragma unroll
    for (int i = 0; i < 8; ++i) {
        int q = i * 64 + l;          // [0,512): 32 rows x 16 chunks
        int lrow = q >> 4;
        int c = q & 15;
        int r = baseRow + lrow;
        if (r < nrows) {
            f16x8 v = *(const f16x8*)&Ob[wave * 32 + lrow][c * 8];
            *(f16x8*)(Y + (size_t)r * 128 + c * 8) = v;
        }
    }
}

// ---------------- GCN aggregation (split-wave, 8B gathers) ----------------
// One wave per node. Lane l: sub-edge (l>>5), feature quad (l&31) -> each gather
// is an 8B dwordx2; two edges in flight per load slot. Cross-half combine via
// shfl_xor(32). out = relu(dinv[i]*(sum hw'[col] + hw'[i]) + b), fp16 out.

__device__ __forceinline__ void acc_h4(float4& a, float2 raw) {
    __half2 lo = *(__half2*)&raw.x;
    __half2 hi = *(__half2*)&raw.y;
    float2 f0 = __half22float2(lo);
    float2 f1 = __half22float2(hi);
    a.x += f0.x; a.y += f0.y; a.z += f1.x; a.w += f1.y;
}

__global__ __launch_bounds__(256) void aggregate_kernel(const __half* __restrict__ hw,
                                                        const int* __restrict__ rp,
                                                        const int* __restrict__ col,
                                                        const float* __restrict__ dinv,
                                                        const float* __restrict__ bias,
                                                        __half* __restrict__ outp, int n) {
    int wid = threadIdx.x >> 6;
    int lane = threadIdx.x & 63;
    int i = blockIdx.x * 4 + wid;
    if (i >= n) return;
    int sub = lane >> 5;     // which edge of the pair
    int q = lane & 31;       // feature quad (4 halves = 8B)
    const float2* hw4 = (const float2*)hw;   // row = 32 x 8B chunks

    float4 b0 = {0.f, 0.f, 0.f, 0.f};
    float4 b1 = {0.f, 0.f, 0.f, 0.f};
    float4 b2 = {0.f, 0.f, 0.f, 0.f};
    float4 b3 = {0.f, 0.f, 0.f, 0.f};

    if (sub == 0) acc_h4(b2, hw4[(size_t)i * 32 + q]);   // self term

    int j0 = rp[i], j1 = rp[i + 1];
    int m = j1 - j0;
    int pairs = m >> 1;
    int j = j0;
    for (; pairs >= 4; pairs -= 4, j += 8) {
        int e0 = __builtin_nontemporal_load(col + j + 0 + sub);
        int e1 = __builtin_nontemporal_load(col + j + 2 + sub);
        int e2 = __builtin_nontemporal_load(col + j + 4 + sub);
        int e3 = __builtin_nontemporal_load(col + j + 6 + sub);
        float2 r0 = hw4[(size_t)e0 * 32 + q];
        float2 r1 = hw4[(size_t)e1 * 32 + q];
        float2 r2 = hw4[(size_t)e2 * 32 + q];
        float2 r3 = hw4[(size_t)e3 * 32 + q];
        acc_h4(b0, r0);
        acc_h4(b1, r1);
        acc_h4(b2, r2);
        acc_h4(b3, r3);
    }
    for (; pairs > 0; --pairs, j += 2) {
        int e = __builtin_nontemporal_load(col + j + sub);
        acc_h4(b0, hw4[(size_t)e * 32 + q]);
    }
    if ((m & 1) && sub == 0) {
        int e = __builtin_nontemporal_load(col + j1 - 1);
        acc_h4(b1, hw4[(size_t)e * 32 + q]);
    }

    float4 acc;
    acc.x = (b0.x + b1.x) + (b2.x + b3.x);
    acc.y = (b0.y + b1.y) + (b2.y + b3.y);
    acc.z = (b0.z + b1.z) + (b2.z + b3.z);
    acc.w = (b0.w + b1.w) + (b2.w + b3.w);
    // combine the two half-wave partials
    acc.x += __shfl_xor(acc.x, 32);
    acc.y += __shfl_xor(acc.y, 32);
    acc.z += __shfl_xor(acc.z, 32);
    acc.w += __shfl_xor(acc.w, 32);

    if (sub == 0) {
        float di = dinv[i];
        float4 bv = ((const float4*)bias)[q];
        float rx = fmaxf(acc.x * di + bv.x, 0.f);
        float ry = fmaxf(acc.y * di + bv.y, 0.f);
        float rz = fmaxf(acc.z * di + bv.z, 0.f);
        float rw = fmaxf(acc.w * di + bv.w, 0.f);
        float2 pk;
        *(__half2*)&pk.x = __floats2half2_rn(rx, ry);
        *(__half2*)&pk.y = __floats2half2_rn(rz, rw);
        ((float2*)outp)[(size_t)i * 32 + q] = pk;
    }
}

// ---------------- mean pool (50 consecutive fp16 rows per graph) ----------------

__global__ __launch_bounds__(256) void pool_kernel(const __half* __restrict__ h,
                                                   float* __restrict__ gemb) {
    int wid = threadIdx.x >> 6;
    int lane = threadIdx.x & 63;
    int g = blockIdx.x * 4 + wid;
    if (g >= GG) return;
    const __half2* h2 = (const __half2*)h;
    float2 acc = {0.f, 0.f};
    size_t base = (size_t)g * NPG * 64;
    for (int r = 0; r < NPG; ++r) {
        float2 v = __half22float2(h2[base + (size_t)r * 64 + lane]);
        acc.x += v.x;
        acc.y += v.y;
    }
    float2 o;
    o.x = acc.x / (float)NPG;
    o.y = acc.y / (float)NPG;
    ((float2*)gemb)[(size_t)g * 64 + lane] = o;
}

// ---------------- DeepSets psi: p_g = tanh(relu(emb W1 + b1) W2 + b2) ----------------

__global__ __launch_bounds__(128) void psi_kernel(const float* __restrict__ gemb,
                                                  const float* __restrict__ W1,
                                                  const float* __restrict__ b1,
                                                  const float* __restrict__ W2,
                                                  const float* __restrict__ b2,
                                                  float* __restrict__ pbuf) {
    __shared__ float e[128];
    __shared__ float t[128];
    int g = blockIdx.x;
    int c = threadIdx.x;
    e[c] = gemb[(size_t)g * 128 + c];
    __syncthreads();
    float acc = b1[c];
#pragma unroll 8
    for (int k = 0; k < 128; ++k) acc += e[k] * W1[k * 128 + c];
    t[c] = fmaxf(acc, 0.f);
    __syncthreads();
    float acc2 = b2[c];
#pragma unroll 8
    for (int k = 0; k < 128; ++k) acc2 += t[k] * W2[k * 128 + c];
    pbuf[(size_t)g * 128 + c] = tanhf(acc2);
}

// ---------------- set-sum + phi head ----------------

__global__ __launch_bounds__(128) void phi_kernel(const float* __restrict__ pbuf,
                                                  const float* __restrict__ W1,
                                                  const float* __restrict__ b1,
                                                  const float* __restrict__ W2,
                                                  const float* __restrict__ b2,
                                                  float* __restrict__ out) {
    __shared__ float a[128];
    __shared__ float u[128];
    int s = blockIdx.x;
    int c = threadIdx.x;
    float acc = 0.f;
#pragma unroll
    for (int p = 0; p < PGS; ++p) acc += pbuf[(size_t)(s + p * SS) * 128 + c];
    a[c] = acc;
    __syncthreads();
    float acc1 = b1[c];
#pragma unroll 8
    for (int k = 0; k < 128; ++k) acc1 += a[k] * W1[k * 128 + c];
    u[c] = fmaxf(acc1, 0.f);
    __syncthreads();
    if (c < CC) {
        float acc2 = b2[c];
#pragma unroll 8
        for (int k = 0; k < 128; ++k) acc2 += u[k] * W2[k * CC + c];
        out[(size_t)s * CC + c] = acc2;
    }
}

// ---------------- launch ----------------

extern "C" void kernel_launch(void* const* d_in, const int* in_sizes, int n_in,
                              void* d_out, int out_size, void* d_ws, size_t ws_size,
                              hipStream_t stream) {
    const float* x   = (const float*)d_in[0];
    const int* ei    = (const int*)d_in[1];
    const float* W1  = (const float*)d_in[4];
    const float* b1  = (const float*)d_in[5];
    const float* W2  = (const float*)d_in[6];
    const float* b2  = (const float*)d_in[7];
    const float* W3  = (const float*)d_in[8];
    const float* b3  = (const float*)d_in[9];
    const float* pW1 = (const float*)d_in[10];
    const float* pb1 = (const float*)d_in[11];
    const float* pW2 = (const float*)d_in[12];
    const float* pb2 = (const float*)d_in[13];
    const float* fW1 = (const float*)d_in[14];
    const float* fb1 = (const float*)d_in[15];
    const float* fW2 = (const float*)d_in[16];
    const float* fb2 = (const float*)d_in[17];
    float* out = (float*)d_out;

    // workspace carve-up (256B aligned)
    char* p = (char*)d_ws;
    auto alloc = [&](size_t bytes) {
        char* r = p;
        p += (bytes + 255) & ~(size_t)255;
        return r;
    };
    float*     dinv    = (float*)alloc((size_t)NN * 4);
    int*       row_ptr = (int*)alloc((size_t)(NN + 1) * 4);
    int*       bsum2   = (int*)alloc(512 * 4);
    int*       blkcnt  = (int*)alloc((size_t)SCAN_N * 4);
    int*       blkoff  = (int*)alloc((size_t)(SCAN_N + 1) * 4);
    int*       col     = (int*)alloc((size_t)EE * 4);
    long long* ebin    = (long long*)alloc((size_t)EE * 8);      // 12.8 MB packed buckets
    _Float16*  bufA    = (_Float16*)alloc((size_t)NN * HH * 2);  // dinv-scaled XW (gather operand)
    __half*    bufB    = (__half*)alloc((size_t)NN * HH * 2);    // relu'd layer output
    float*     gemb    = (float*)alloc((size_t)GG * HH * 4);
    float*     pbuf    = (float*)alloc((size_t)GG * HH * 4);

    const int nblkS = (SCAN_N + 255) / 256;    // 196

    // CSR build (deterministic binned, class-owned)
    histo_kernel<<<NBLKH, 256, 0, stream>>>(ei + EE, blkcnt);
    scan_chunk_kernel<<<nblkS, 256, 0, stream>>>(blkcnt, blkoff, bsum2, SCAN_N);
    scan_bsums_kernel<<<1, 512, 0, stream>>>(bsum2, nblkS);
    scan_finish_kernel<<<nblkS, 256, 0, stream>>>(blkoff, bsum2, SCAN_N);
    scatter_bin_kernel<<<NBLKH, 256, 0, stream>>>(ei, blkoff, ebin);
    count_dinv_kernel<<<NCLS, 256, 0, stream>>>(ebin, blkoff, row_ptr, dinv);
    fill_class_kernel<<<NCLS, 256, 0, stream>>>(ebin, blkoff, row_ptr, col);

    const int gemmBlocks = (NN + 127) / 128;   // 782
    const int aggBlocks  = (NN + 3) / 4;       // 25000

    // layer 1
    gemm_mfma_kernel<true><<<gemmBlocks, 256, 0, stream>>>(x, W1, dinv, bufA, NN);
    aggregate_kernel<<<aggBlocks, 256, 0, stream>>>((const __half*)bufA, row_ptr, col, dinv, b1, bufB, NN);
    // layer 2
    gemm_mfma_kernel<false><<<gemmBlocks, 256, 0, stream>>>(bufB, W2, dinv, bufA, NN);
    aggregate_kernel<<<aggBlocks, 256, 0, stream>>>((const __half*)bufA, row_ptr, col, dinv, b2, bufB, NN);
    // layer 3
    gemm_mfma_kernel<false><<<gemmBlocks, 256, 0, stream>>>(bufB, W3, dinv, bufA, NN);
    aggregate_kernel<<<aggBlocks, 256, 0, stream>>>((const __half*)bufA, row_ptr, col, dinv, b3, bufB, NN);

    // pool -> [G,H]
    pool_kernel<<<(GG + 3) / 4, 256, 0, stream>>>(bufB, gemb);
    // DeepSets
    psi_kernel<<<GG, 128, 0, stream>>>(gemb, pW1, pb1, pW2, pb2, pbuf);
    phi_kernel<<<SS, 128, 0, stream>>>(pbuf, fW1, fb1, fW2, fb2, out);
}

// Round 12
// 374.891 us; speedup vs baseline: 1.1139x; 1.1139x over previous
//
#include <hip/hip_runtime.h>
#include <hip/hip_bf16.h>
#include <hip/hip_fp16.h>
#include <math.h>

// Problem constants (match reference)
#define NN 100000
#define EE 1600000
#define HH 128
#define GG 2000
#define SS 200
#define CC 10
#define NPG 50   // nodes per graph
#define PGS 10   // graphs per set
#define NCLS 128           // dst classes (one persistent block per class in count/fill)
#define CLSW 782           // ceil(NN/NCLS); 128*782 = 100096 >= NN
#define EPB 4096           // edges per histogram/scatter block
#define NBLKH 391          // ceil(EE/EPB)
#define SCAN_N (NCLS * NBLKH)   // 50048

typedef _Float16 f16x8 __attribute__((ext_vector_type(8)));
typedef float    f32x4 __attribute__((ext_vector_type(4)));

// packed edge-in-bin: bits [16:0] = src (<131072), bits [26:17] = d - class_base (<1024)

// ---------------- CSR build (deterministic binned, class-owned fill) ----------------

// Step 1: per-block per-class histogram (LDS only)
__global__ __launch_bounds__(256) void histo_kernel(const int* __restrict__ ei_dst,
                                                    int* __restrict__ blkcnt) {
    __shared__ int h[4][NCLS];
    for (int i = threadIdx.x; i < 4 * NCLS; i += 256) ((int*)h)[i] = 0;
    __syncthreads();
    int w = threadIdx.x >> 6;
    int base = blockIdx.x * EPB;
#pragma unroll
    for (int i = 0; i < 16; ++i) {
        int idx = base + i * 256 + threadIdx.x;
        if (idx < EE) {
            int d = __builtin_nontemporal_load(ei_dst + idx);
            atomicAdd(&h[w][(unsigned)d / CLSW], 1);
        }
    }
    __syncthreads();
    for (int c = threadIdx.x; c < NCLS; c += 256)
        blkcnt[c * NBLKH + blockIdx.x] = h[0][c] + h[1][c] + h[2][c] + h[3][c];
}

// generic 3-phase scan: out[i+1] = inclusive_scan(v)[i], out[0] = 0  (=> out = exclusive scan)
__global__ void scan_chunk_kernel(const int* __restrict__ v, int* __restrict__ outp,
                                  int* __restrict__ bsum, int n) {
    __shared__ int s[256];
    int tid = threadIdx.x;
    int i = blockIdx.x * 256 + tid;
    int x = (i < n) ? v[i] : 0;
    s[tid] = x;
    __syncthreads();
    for (int off = 1; off < 256; off <<= 1) {
        int y = (tid >= off) ? s[tid - off] : 0;
        __syncthreads();
        s[tid] += y;
        __syncthreads();
    }
    if (i < n) outp[i + 1] = s[tid];
    if (tid == 255) bsum[blockIdx.x] = s[255];
}

__global__ void scan_bsums_kernel(int* bsum, int nb) {
    __shared__ int s[512];
    int tid = threadIdx.x;
    int x = (tid < nb) ? bsum[tid] : 0;
    s[tid] = x;
    __syncthreads();
    for (int off = 1; off < 512; off <<= 1) {
        int y = (tid >= off) ? s[tid - off] : 0;
        __syncthreads();
        s[tid] += y;
        __syncthreads();
    }
    if (tid < nb) bsum[tid] = s[tid];
}

__global__ void scan_finish_kernel(int* __restrict__ outp, const int* __restrict__ bsum, int n) {
    int i = blockIdx.x * 256 + threadIdx.x;
    if (i < n) {
        if (blockIdx.x > 0) outp[i + 1] += bsum[blockIdx.x - 1];
    }
    if (i == 0) outp[0] = 0;
}

// Step 3: scatter edges into packed class buckets (LDS cursors only, 4B payload)
__global__ __launch_bounds__(256) void scatter_bin_kernel(const int* __restrict__ ei,
                                                          const int* __restrict__ blkoff,
                                                          unsigned int* __restrict__ ebin) {
    __shared__ int cur[NCLS];
    for (int c = threadIdx.x; c < NCLS; c += 256) cur[c] = blkoff[c * NBLKH + blockIdx.x];
    __syncthreads();
    int base = blockIdx.x * EPB;
#pragma unroll
    for (int i = 0; i < 16; ++i) {
        int idx = base + i * 256 + threadIdx.x;
        if (idx < EE) {
            int s = __builtin_nontemporal_load(ei + idx);
            int d = __builtin_nontemporal_load(ei + EE + idx);
            int c = (unsigned)d / CLSW;
            int pos = atomicAdd(&cur[c], 1);
            ebin[pos] = ((unsigned)(d - c * CLSW) << 17) | (unsigned)s;
        }
    }
}

// Step 4: one block per class: LDS degree count -> row_ptr (class-local prefix scan) + dinv.
__global__ __launch_bounds__(256) void count_dinv_kernel(const unsigned int* __restrict__ ebin,
                                                         const int* __restrict__ blkoff,
                                                         int* __restrict__ row_ptr,
                                                         float* __restrict__ dinv) {
    __shared__ int cnt[CLSW];
    __shared__ int part[256];
    int c = blockIdx.x;
    for (int i = threadIdx.x; i < CLSW; i += 256) cnt[i] = 0;
    __syncthreads();
    int beg = blkoff[c * NBLKH];
    int end = blkoff[(c + 1) * NBLKH];   // blkoff[SCAN_N] == EE
    int n0 = c * CLSW;
    for (int k = beg + threadIdx.x; k < end; k += 256) {
        unsigned int e = __builtin_nontemporal_load(ebin + k);
        atomicAdd(&cnt[e >> 17], 1);
    }
    __syncthreads();
    int nn = min(n0 + CLSW, NN) - n0;
    int t = threadIdx.x;
    int base = t * 4;
    int lpre[4];
    int lsum = 0;
#pragma unroll
    for (int i = 0; i < 4; ++i) {
        int idx = base + i;
        int v = (idx < nn) ? cnt[idx] : 0;
        lpre[i] = lsum;
        lsum += v;
    }
    part[t] = lsum;
    __syncthreads();
    for (int off = 1; off < 256; off <<= 1) {
        int y = (t >= off) ? part[t - off] : 0;
        __syncthreads();
        part[t] += y;
        __syncthreads();
    }
    int add = beg + ((t > 0) ? part[t - 1] : 0);
#pragma unroll
    for (int i = 0; i < 4; ++i) {
        int idx = base + i;
        if (idx < nn) {
            row_ptr[n0 + idx] = add + lpre[i];
            dinv[n0 + idx] = 1.0f / sqrtf((float)(cnt[idx] + 1));  // +1 self loop
        }
    }
    if (t == 0) row_ptr[n0 + nn] = end;   // class boundary (last class writes row_ptr[NN]=EE)
}

// Step 5: one block per class: LDS cursors from row_ptr, fill col (class-owned col range).
__global__ __launch_bounds__(256) void fill_class_kernel(const unsigned int* __restrict__ ebin,
                                                         const int* __restrict__ blkoff,
                                                         const int* __restrict__ row_ptr,
                                                         int* __restrict__ col) {
    __shared__ int cur[CLSW];
    int c = blockIdx.x;
    int n0 = c * CLSW;
    int nn = min(n0 + CLSW, NN) - n0;
    for (int i = threadIdx.x; i < nn; i += 256) cur[i] = row_ptr[n0 + i];
    __syncthreads();
    int beg = blkoff[c * NBLKH];
    int end = blkoff[(c + 1) * NBLKH];
    for (int k = beg + threadIdx.x; k < end; k += 256) {
        unsigned int e = __builtin_nontemporal_load(ebin + k);
        int o = atomicAdd(&cur[e >> 17], 1);
        col[o] = (int)(e & 0x1FFFFu);
    }
}

// ---------------- MFMA GEMM: Y[n][128](fp16, x dinv[row]) = X[n][128] @ W[128][128] ----------

#define WTP 136

template <bool IN32>
__global__ __launch_bounds__(256) void gemm_mfma_kernel(const void* __restrict__ Xv,
                                                        const float* __restrict__ W,
                                                        const float* __restrict__ dinv,
                                                        _Float16* __restrict__ Y, int nrows) {
    __shared__ _Float16 Wt[128][WTP];   // 34.8 KB
    __shared__ _Float16 Ob[128][WTP];   // 34.8 KB
    int tid = threadIdx.x;
    int row0 = blockIdx.x * 128;

    // stage W transposed as fp16
    const float4* W4 = (const float4*)W;
#pragma unroll
    for (int it = 0; it < 16; ++it) {
        int f = it * 256 + tid;      // float4 id in [0,4096)
        int k = f >> 5;              // W row
        int c = (f & 31) << 2;       // W col (x4)
        float4 v = W4[f];
        Wt[c + 0][k] = (_Float16)v.x;
        Wt[c + 1][k] = (_Float16)v.y;
        Wt[c + 2][k] = (_Float16)v.z;
        Wt[c + 3][k] = (_Float16)v.w;
    }
    __syncthreads();

    int wave = tid >> 6;
    int l = tid & 63;
    int arow = l & 15;
    int kg = l >> 4;                 // k-group 0..3
    int baseRow = row0 + wave * 32;

    // A fragments: lane holds X[row][ks*32 + kg*8 .. +8]
    f16x8 afrag[2][4];
#pragma unroll
    for (int rt = 0; rt < 2; ++rt) {
        int r = baseRow + rt * 16 + arow;
        r = min(r, nrows - 1);
        if (IN32) {
            const float* xr = ((const float*)Xv) + (size_t)r * 128;
#pragma unroll
            for (int ks = 0; ks < 4; ++ks) {
                int k0 = ks * 32 + kg * 8;
                float4 a = ((const float4*)xr)[k0 >> 2];
                float4 b = ((const float4*)xr)[(k0 >> 2) + 1];
                f16x8 v;
                v[0] = (_Float16)a.x; v[1] = (_Float16)a.y;
                v[2] = (_Float16)a.z; v[3] = (_Float16)a.w;
                v[4] = (_Float16)b.x; v[5] = (_Float16)b.y;
                v[6] = (_Float16)b.z; v[7] = (_Float16)b.w;
                afrag[rt][ks] = v;
            }
        } else {
            const f16x8* xr = (const f16x8*)(((const _Float16*)Xv) + (size_t)r * 128);
#pragma unroll
            for (int ks = 0; ks < 4; ++ks) afrag[rt][ks] = xr[ks * 4 + kg];
        }
    }

    f32x4 acc[2][8];
#pragma unroll
    for (int rt = 0; rt < 2; ++rt)
#pragma unroll
        for (int ct = 0; ct < 8; ++ct) acc[rt][ct] = (f32x4){0.f, 0.f, 0.f, 0.f};

#pragma unroll
    for (int ct = 0; ct < 8; ++ct) {
#pragma unroll
        for (int ks = 0; ks < 4; ++ks) {
            f16x8 b = *(const f16x8*)&Wt[ct * 16 + arow][ks * 32 + kg * 8];
            acc[0][ct] = __builtin_amdgcn_mfma_f32_16x16x32_f16(afrag[0][ks], b, acc[0][ct], 0, 0, 0);
            acc[1][ct] = __builtin_amdgcn_mfma_f32_16x16x32_f16(afrag[1][ks], b, acc[1][ct], 0, 0, 0);
        }
    }

    // dinv for the 8 rows this lane owns (D: row = rt*16 + 4*kg + j, col = arow)
    float dv[2][4];
#pragma unroll
    for (int rt = 0; rt < 2; ++rt)
#pragma unroll
        for (int j = 0; j < 4; ++j) {
            int r = baseRow + rt * 16 + 4 * kg + j;
            dv[rt][j] = dinv[min(r, nrows - 1)];
        }

    // stage to LDS (own wave's 32 rows only — no block sync needed)
#pragma unroll
    for (int rt = 0; rt < 2; ++rt)
#pragma unroll
        for (int ct = 0; ct < 8; ++ct)
#pragma unroll
            for (int j = 0; j < 4; ++j)
                Ob[wave * 32 + rt * 16 + 4 * kg + j][ct * 16 + arow] =
                    (_Float16)(acc[rt][ct][j] * dv[rt][j]);

    // coalesced write-back: 8 x 16B per lane
#pragma unroll
    for (int i = 0; i < 8; ++i) {
        int q = i * 64 + l;          // [0,512): 32 rows x 16 chunks
        int lrow = q >> 4;
        int c = q & 15;
        int r = baseRow + lrow;
        if (r < nrows) {
            f16x8 v = *(const f16x8*)&Ob[wave * 32 + lrow][c * 8];
            *(f16x8*)(Y + (size_t)r * 128 + c * 8) = v;
        }
    }
}

// ---------------- GCN aggregation (R10 proven version) ----------------
// one wave per node, lane = half2 feature slot; edge loop unrolled x8 with 4
// independent accumulators. out = relu(dinv[i]*(sum hw'[col] + hw'[i]) + b), fp16 out.

__global__ __launch_bounds__(256) void aggregate_kernel(const __half* __restrict__ hw,
                                                        const int* __restrict__ rp,
                                                        const int* __restrict__ col,
                                                        const float* __restrict__ dinv,
                                                        const float* __restrict__ bias,
                                                        __half* __restrict__ outp, int n) {
    int wid = threadIdx.x >> 6;
    int lane = threadIdx.x & 63;
    int i = blockIdx.x * 4 + wid;
    if (i >= n) return;
    const __half2* hw2 = (const __half2*)hw;  // row = 64 half2 (256B)
    float2 a0, a1, a2, a3;
    {
        float2 self = __half22float2(hw2[(size_t)i * 64 + lane]);
        a0.x = self.x; a0.y = self.y;
    }
    a1 = make_float2(0.f, 0.f);
    a2 = make_float2(0.f, 0.f);
    a3 = make_float2(0.f, 0.f);
    int j0 = rp[i], j1 = rp[i + 1];
    int j = j0;
    for (; j + 8 <= j1; j += 8) {
        int s0 = col[j + 0];
        int s1 = col[j + 1];
        int s2 = col[j + 2];
        int s3 = col[j + 3];
        int s4 = col[j + 4];
        int s5 = col[j + 5];
        int s6 = col[j + 6];
        int s7 = col[j + 7];
        __half2 v0 = hw2[(size_t)s0 * 64 + lane];
        __half2 v1 = hw2[(size_t)s1 * 64 + lane];
        __half2 v2 = hw2[(size_t)s2 * 64 + lane];
        __half2 v3 = hw2[(size_t)s3 * 64 + lane];
        __half2 v4 = hw2[(size_t)s4 * 64 + lane];
        __half2 v5 = hw2[(size_t)s5 * 64 + lane];
        __half2 v6 = hw2[(size_t)s6 * 64 + lane];
        __half2 v7 = hw2[(size_t)s7 * 64 + lane];
        float2 f;
        f = __half22float2(v0); a0.x += f.x; a0.y += f.y;
        f = __half22float2(v1); a1.x += f.x; a1.y += f.y;
        f = __half22float2(v2); a2.x += f.x; a2.y += f.y;
        f = __half22float2(v3); a3.x += f.x; a3.y += f.y;
        f = __half22float2(v4); a0.x += f.x; a0.y += f.y;
        f = __half22float2(v5); a1.x += f.x; a1.y += f.y;
        f = __half22float2(v6); a2.x += f.x; a2.y += f.y;
        f = __half22float2(v7); a3.x += f.x; a3.y += f.y;
    }
    for (; j + 4 <= j1; j += 4) {
        int s0 = col[j + 0];
        int s1 = col[j + 1];
        int s2 = col[j + 2];
        int s3 = col[j + 3];
        __half2 v0 = hw2[(size_t)s0 * 64 + lane];
        __half2 v1 = hw2[(size_t)s1 * 64 + lane];
        __half2 v2 = hw2[(size_t)s2 * 64 + lane];
        __half2 v3 = hw2[(size_t)s3 * 64 + lane];
        float2 f;
        f = __half22float2(v0); a0.x += f.x; a0.y += f.y;
        f = __half22float2(v1); a1.x += f.x; a1.y += f.y;
        f = __half22float2(v2); a2.x += f.x; a2.y += f.y;
        f = __half22float2(v3); a3.x += f.x; a3.y += f.y;
    }
    for (; j < j1; ++j) {
        int s = col[j];
        float2 f = __half22float2(hw2[(size_t)s * 64 + lane]);
        a0.x += f.x; a0.y += f.y;
    }
    float di = dinv[i];
    float2 acc;
    acc.x = ((a0.x + a1.x) + (a2.x + a3.x)) * di;
    acc.y = ((a0.y + a1.y) + (a2.y + a3.y)) * di;
    float2 bv = ((const float2*)bias)[lane];
    float rx = fmaxf(acc.x + bv.x, 0.f);
    float ry = fmaxf(acc.y + bv.y, 0.f);
    ((__half2*)outp)[(size_t)i * 64 + lane] = __floats2half2_rn(rx, ry);
}

// ---------------- mean pool (50 consecutive fp16 rows per graph) ----------------

__global__ __launch_bounds__(256) void pool_kernel(const __half* __restrict__ h,
                                                   float* __restrict__ gemb) {
    int wid = threadIdx.x >> 6;
    int lane = threadIdx.x & 63;
    int g = blockIdx.x * 4 + wid;
    if (g >= GG) return;
    const __half2* h2 = (const __half2*)h;
    float2 acc = {0.f, 0.f};
    size_t base = (size_t)g * NPG * 64;
    for (int r = 0; r < NPG; ++r) {
        float2 v = __half22float2(h2[base + (size_t)r * 64 + lane]);
        acc.x += v.x;
        acc.y += v.y;
    }
    float2 o;
    o.x = acc.x / (float)NPG;
    o.y = acc.y / (float)NPG;
    ((float2*)gemb)[(size_t)g * 64 + lane] = o;
}

// ---------------- DeepSets psi: p_g = tanh(relu(emb W1 + b1) W2 + b2) ----------------

__global__ __launch_bounds__(128) void psi_kernel(const float* __restrict__ gemb,
                                                  const float* __restrict__ W1,
                                                  const float* __restrict__ b1,
                                                  const float* __restrict__ W2,
                                                  const float* __restrict__ b2,
                                                  float* __restrict__ pbuf) {
    __shared__ float e[128];
    __shared__ float t[128];
    int g = blockIdx.x;
    int c = threadIdx.x;
    e[c] = gemb[(size_t)g * 128 + c];
    __syncthreads();
    float acc = b1[c];
#pragma unroll 8
    for (int k = 0; k < 128; ++k) acc += e[k] * W1[k * 128 + c];
    t[c] = fmaxf(acc, 0.f);
    __syncthreads();
    float acc2 = b2[c];
#pragma unroll 8
    for (int k = 0; k < 128; ++k) acc2 += t[k] * W2[k * 128 + c];
    pbuf[(size_t)g * 128 + c] = tanhf(acc2);
}

// ---------------- set-sum + phi head ----------------

__global__ __launch_bounds__(128) void phi_kernel(const float* __restrict__ pbuf,
                                                  const float* __restrict__ W1,
                                                  const float* __restrict__ b1,
                                                  const float* __restrict__ W2,
                                                  const float* __restrict__ b2,
                                                  float* __restrict__ out) {
    __shared__ float a[128];
    __shared__ float u[128];
    int s = blockIdx.x;
    int c = threadIdx.x;
    float acc = 0.f;
#pragma unroll
    for (int p = 0; p < PGS; ++p) acc += pbuf[(size_t)(s + p * SS) * 128 + c];
    a[c] = acc;
    __syncthreads();
    float acc1 = b1[c];
#pragma unroll 8
    for (int k = 0; k < 128; ++k) acc1 += a[k] * W1[k * 128 + c];
    u[c] = fmaxf(acc1, 0.f);
    __syncthreads();
    if (c < CC) {
        float acc2 = b2[c];
#pragma unroll 8
        for (int k = 0; k < 128; ++k) acc2 += u[k] * W2[k * CC + c];
        out[(size_t)s * CC + c] = acc2;
    }
}

// ---------------- launch ----------------

extern "C" void kernel_launch(void* const* d_in, const int* in_sizes, int n_in,
                              void* d_out, int out_size, void* d_ws, size_t ws_size,
                              hipStream_t stream) {
    const float* x   = (const float*)d_in[0];
    const int* ei    = (const int*)d_in[1];
    const float* W1  = (const float*)d_in[4];
    const float* b1  = (const float*)d_in[5];
    const float* W2  = (const float*)d_in[6];
    const float* b2  = (const float*)d_in[7];
    const float* W3  = (const float*)d_in[8];
    const float* b3  = (const float*)d_in[9];
    const float* pW1 = (const float*)d_in[10];
    const float* pb1 = (const float*)d_in[11];
    const float* pW2 = (const float*)d_in[12];
    const float* pb2 = (const float*)d_in[13];
    const float* fW1 = (const float*)d_in[14];
    const float* fb1 = (const float*)d_in[15];
    const float* fW2 = (const float*)d_in[16];
    const float* fb2 = (const float*)d_in[17];
    float* out = (float*)d_out;

    // workspace carve-up (256B aligned)
    char* p = (char*)d_ws;
    auto alloc = [&](size_t bytes) {
        char* r = p;
        p += (bytes + 255) & ~(size_t)255;
        return r;
    };
    float*        dinv    = (float*)alloc((size_t)NN * 4);
    int*          row_ptr = (int*)alloc((size_t)(NN + 1) * 4);
    int*          bsum2   = (int*)alloc(512 * 4);
    int*          blkcnt  = (int*)alloc((size_t)SCAN_N * 4);
    int*          blkoff  = (int*)alloc((size_t)(SCAN_N + 1) * 4);
    int*          col     = (int*)alloc((size_t)EE * 4);
    unsigned int* ebin    = (unsigned int*)alloc((size_t)EE * 4);   // 6.4 MB packed buckets
    _Float16*     bufA    = (_Float16*)alloc((size_t)NN * HH * 2);  // dinv-scaled XW (gather operand)
    __half*       bufB    = (__half*)alloc((size_t)NN * HH * 2);    // relu'd layer output
    float*        gemb    = (float*)alloc((size_t)GG * HH * 4);
    float*        pbuf    = (float*)alloc((size_t)GG * HH * 4);

    const int nblkS = (SCAN_N + 255) / 256;    // 196

    // CSR build (deterministic binned, class-owned)
    histo_kernel<<<NBLKH, 256, 0, stream>>>(ei + EE, blkcnt);
    scan_chunk_kernel<<<nblkS, 256, 0, stream>>>(blkcnt, blkoff, bsum2, SCAN_N);
    scan_bsums_kernel<<<1, 512, 0, stream>>>(bsum2, nblkS);
    scan_finish_kernel<<<nblkS, 256, 0, stream>>>(blkoff, bsum2, SCAN_N);
    scatter_bin_kernel<<<NBLKH, 256, 0, stream>>>(ei, blkoff, ebin);
    count_dinv_kernel<<<NCLS, 256, 0, stream>>>(ebin, blkoff, row_ptr, dinv);
    fill_class_kernel<<<NCLS, 256, 0, stream>>>(ebin, blkoff, row_ptr, col);

    const int gemmBlocks = (NN + 127) / 128;   // 782
    const int aggBlocks  = (NN + 3) / 4;       // 25000

    // layer 1
    gemm_mfma_kernel<true><<<gemmBlocks, 256, 0, stream>>>(x, W1, dinv, bufA, NN);
    aggregate_kernel<<<aggBlocks, 256, 0, stream>>>((const __half*)bufA, row_ptr, col, dinv, b1, bufB, NN);
    // layer 2
    gemm_mfma_kernel<false><<<gemmBlocks, 256, 0, stream>>>(bufB, W2, dinv, bufA, NN);
    aggregate_kernel<<<aggBlocks, 256, 0, stream>>>((const __half*)bufA, row_ptr, col, dinv, b2, bufB, NN);
    // layer 3
    gemm_mfma_kernel<false><<<gemmBlocks, 256, 0, stream>>>(bufB, W3, dinv, bufA, NN);
    aggregate_kernel<<<aggBlocks, 256, 0, stream>>>((const __half*)bufA, row_ptr, col, dinv, b3, bufB, NN);

    // pool -> [G,H]
    pool_kernel<<<(GG + 3) / 4, 256, 0, stream>>>(bufB, gemb);
    // DeepSets
    psi_kernel<<<GG, 128, 0, stream>>>(gemb, pW1, pb1, pW2, pb2, pbuf);
    phi_kernel<<<SS, 128, 0, stream>>>(pbuf, fW1, fb1, fW2, fb2, out);
}